// Round 2
// baseline (488.634 us; speedup 1.0000x reference)
//
#include <hip/hip_runtime.h>
#include <hip/hip_bf16.h>
#include <stdint.h>

typedef __attribute__((ext_vector_type(8))) short short8;
typedef __attribute__((ext_vector_type(4))) float f32x4;

#define NROWS  8192
#define DDIM   256
#define HHEADS 4
#define KTOT   1024   // H * D
#define BM     128
#define BN     128
#define BK     64
#define KSTEPS (KTOT / BK)   // 16
#define NTB    (NROWS / BM)  // 64 tile rows
#define NTRI   (NTB * (NTB + 1) / 2)   // 2080 triangular tiles

// round-to-nearest-even float -> bf16 bits
__device__ __forceinline__ unsigned short f2bf(float f) {
  union { float f; uint32_t u; } v;
  v.f = f;
  uint32_t u = v.u;
  uint32_t r = (u + 0x7fffu + ((u >> 16) & 1u)) >> 16;
  return (unsigned short)r;
}

// --------------------------------------------------------------------------
// Kernel 1: Y[n, h*256+d] = bf16( a[h,d]*x[n,d] * rsqrt(max(sum_d (a*x)^2, eps)) )
// --------------------------------------------------------------------------
__global__ __launch_bounds__(256) void prep_y(const float* __restrict__ x,
                                              const float* __restrict__ av,
                                              unsigned short* __restrict__ Y) {
  __shared__ float a_sh[HHEADS][DDIM];
  __shared__ float red[4][HHEADS];

  const int t = threadIdx.x;   // 0..255 == d
  #pragma unroll
  for (int h = 0; h < HHEADS; ++h) a_sh[h][t] = av[h * DDIM + t];
  __syncthreads();

  const int n = blockIdx.x;
  const float xd = x[(size_t)n * DDIM + t];

  float p[HHEADS], s[HHEADS];
  #pragma unroll
  for (int h = 0; h < HHEADS; ++h) {
    p[h] = a_sh[h][t] * xd;
    s[h] = p[h] * p[h];
  }

  #pragma unroll
  for (int off = 32; off > 0; off >>= 1) {
    #pragma unroll
    for (int h = 0; h < HHEADS; ++h) s[h] += __shfl_xor(s[h], off, 64);
  }

  const int wave = t >> 6, lane = t & 63;
  if (lane == 0) {
    #pragma unroll
    for (int h = 0; h < HHEADS; ++h) red[wave][h] = s[h];
  }
  __syncthreads();

  #pragma unroll
  for (int h = 0; h < HHEADS; ++h) {
    const float sum = red[0][h] + red[1][h] + red[2][h] + red[3][h];
    const float rn = rsqrtf(fmaxf(sum, 1e-12f));
    Y[(size_t)n * KTOT + h * DDIM + t] = f2bf(p[h] * rn);
  }
}

// --------------------------------------------------------------------------
// Kernel 2: C = Y * Y^T / 4, exploiting symmetry: only tiles with by >= bx
// are computed; off-diagonal tiles are written twice (straight + LDS-transposed
// mirror).  128x128 tile, BK=64, 4 waves (2x2), 16x16x32 bf16 MFMA.
// --------------------------------------------------------------------------
union SmemU {
  struct { unsigned short A[BM * BK]; unsigned short B[BN * BK]; } s;  // 32 KB
  float tr[32 * 129];  // transpose slice buffer (16.1 KB), aliases staging
};

__global__ __launch_bounds__(256) void gemm_yyt(const unsigned short* __restrict__ Y,
                                                float* __restrict__ C) {
  __shared__ __attribute__((aligned(16))) SmemU sm;

  // bijective XCD swizzle: NTRI = 2080 = 8 * 260
  const int orig = blockIdx.x;
  const int cpx  = NTRI / 8;
  const int wgid = (orig & 7) * cpx + (orig >> 3);

  // triangular decode: wgid -> (by, bx), bx <= by
  int by = (int)((sqrtf(8.0f * (float)wgid + 1.0f) - 1.0f) * 0.5f);
  while ((by + 1) * (by + 2) / 2 <= wgid) ++by;
  while (by * (by + 1) / 2 > wgid) --by;
  const int bx = wgid - by * (by + 1) / 2;

  const int t    = threadIdx.x;
  const int lane = t & 63;
  const int wave = t >> 6;
  const int wr   = wave >> 1;   // 0..1
  const int wc   = wave & 1;    // 0..1

  const int rowA0 = by * BM;    // output row block
  const int rowB0 = bx * BN;    // output col block

  f32x4 acc[4][4];
  #pragma unroll
  for (int i = 0; i < 4; ++i)
    #pragma unroll
    for (int j = 0; j < 4; ++j) acc[i][j] = (f32x4){0.f, 0.f, 0.f, 0.f};

  for (int kt = 0; kt < KSTEPS; ++kt) {
    const int k0 = kt * BK;
    __syncthreads();  // previous compute done before LDS overwrite

    #pragma unroll
    for (int i = 0; i < 4; ++i) {
      const int s     = i * 256 + t;
      const int row   = s >> 3;
      const int gslot = (s & 7) ^ (row & 7);
      const unsigned short* gsrc = Y + (size_t)(rowA0 + row) * KTOT + k0 + gslot * 8;
      unsigned short* ldst = sm.s.A + s * 8;
      __builtin_amdgcn_global_load_lds(
          (__attribute__((address_space(1))) void*)gsrc,
          (__attribute__((address_space(3))) void*)ldst, 16, 0, 0);
    }
    #pragma unroll
    for (int i = 0; i < 4; ++i) {
      const int s     = i * 256 + t;
      const int row   = s >> 3;
      const int gslot = (s & 7) ^ (row & 7);
      const unsigned short* gsrc = Y + (size_t)(rowB0 + row) * KTOT + k0 + gslot * 8;
      unsigned short* ldst = sm.s.B + s * 8;
      __builtin_amdgcn_global_load_lds(
          (__attribute__((address_space(1))) void*)gsrc,
          (__attribute__((address_space(3))) void*)ldst, 16, 0, 0);
    }
    __syncthreads();

    #pragma unroll
    for (int ks = 0; ks < 2; ++ks) {
      short8 af[4], bfr[4];
      #pragma unroll
      for (int mr = 0; mr < 4; ++mr) {
        const int row  = wr * 64 + mr * 16 + (lane & 15);
        const int slot = (ks * 4 + (lane >> 4)) ^ (row & 7);
        af[mr] = *(const short8*)(sm.s.A + row * BK + slot * 8);
      }
      #pragma unroll
      for (int nr = 0; nr < 4; ++nr) {
        const int row  = wc * 64 + nr * 16 + (lane & 15);
        const int slot = (ks * 4 + (lane >> 4)) ^ (row & 7);
        bfr[nr] = *(const short8*)(sm.s.B + row * BK + slot * 8);
      }
      #pragma unroll
      for (int mr = 0; mr < 4; ++mr)
        #pragma unroll
        for (int nr = 0; nr < 4; ++nr)
          acc[mr][nr] = __builtin_amdgcn_mfma_f32_16x16x32_bf16(
              af[mr], bfr[nr], acc[mr][nr], 0, 0, 0);
    }
  }

  // ---- straight write: C[rowA0 + r][rowB0 + c] ----
  // C/D layout: col = lane&15, row = (lane>>4)*4 + r  (m89/m91)
  const int crow0 = rowA0 + wr * 64;
  const int ccol  = rowB0 + wc * 64 + (lane & 15);
  #pragma unroll
  for (int mr = 0; mr < 4; ++mr) {
    #pragma unroll
    for (int nr = 0; nr < 4; ++nr) {
      #pragma unroll
      for (int r = 0; r < 4; ++r) {
        const int row = crow0 + mr * 16 + (lane >> 4) * 4 + r;
        C[(size_t)row * NROWS + ccol + nr * 16] = acc[mr][nr][r] * 0.25f;
      }
    }
  }

  // ---- mirror write: C[rowB0 + c][rowA0 + r] = tile[r][c], via LDS ----
  if (by != bx) {
    float (*tr)[129] = (float(*)[129])sm.tr;
    #pragma unroll 1
    for (int c0 = 0; c0 < 128; c0 += 32) {
      __syncthreads();  // buffer free (covers staging reuse on first iter)
      if (wc == (c0 >> 6)) {
        const int nrbase = (c0 & 63) >> 4;   // 0 or 2
        #pragma unroll
        for (int nn = 0; nn < 2; ++nn) {
          const int nr = nrbase + nn;
          const int i  = nn * 16 + (lane & 15);          // c - c0
          #pragma unroll
          for (int mr = 0; mr < 4; ++mr) {
            #pragma unroll
            for (int r = 0; r < 4; ++r) {
              const int j = wr * 64 + mr * 16 + (lane >> 4) * 4 + r;  // r index
              tr[i][j] = acc[mr][nr][r];
            }
          }
        }
      }
      __syncthreads();
      // write 32x128 slice: rows rowB0+c0+ii, cols rowA0+jj (coalesced)
      #pragma unroll
      for (int q = 0; q < 16; ++q) {
        const int idx = q * 256 + t;    // 0..4095
        const int ii  = idx >> 7;
        const int jj  = idx & 127;
        C[(size_t)(rowB0 + c0 + ii) * NROWS + rowA0 + jj] = tr[ii][jj] * 0.25f;
      }
    }
  }
}

// --------------------------------------------------------------------------
extern "C" void kernel_launch(void* const* d_in, const int* in_sizes, int n_in,
                              void* d_out, int out_size, void* d_ws, size_t ws_size,
                              hipStream_t stream) {
  (void)in_sizes; (void)n_in; (void)out_size; (void)ws_size;
  const float* x  = (const float*)d_in[0];   // [8192, 256] f32
  const float* av = (const float*)d_in[1];   // [4, 256] f32
  float* C = (float*)d_out;                  // [8192, 8192] f32
  unsigned short* Y = (unsigned short*)d_ws; // [8192, 1024] bf16 (16 MB scratch)

  prep_y<<<NROWS, 256, 0, stream>>>(x, av, Y);
  gemm_yyt<<<NTRI, 256, 0, stream>>>(Y, C);
}

// Round 3
// 150.015 us; speedup vs baseline: 3.2572x; 3.2572x over previous
//
#include <hip/hip_runtime.h>
#include <hip/hip_bf16.h>
#include <stdint.h>

typedef __attribute__((ext_vector_type(8))) short short8;
typedef __attribute__((ext_vector_type(4))) float f32x4;

#define NROWS  8192
#define DDIM   256
#define HHEADS 4
#define KTOT   1024   // H * D
#define BM     128
#define BN     128
#define BK     64
#define KSTEPS (KTOT / BK)   // 16
#define NTB    (NROWS / BM)  // 64 tile rows
#define NTRI   (NTB * (NTB + 1) / 2)   // 2080 triangular tiles

// round-to-nearest-even float -> bf16 bits
__device__ __forceinline__ unsigned short f2bf(float f) {
  union { float f; uint32_t u; } v;
  v.f = f;
  uint32_t u = v.u;
  uint32_t r = (u + 0x7fffu + ((u >> 16) & 1u)) >> 16;
  return (unsigned short)r;
}

// --------------------------------------------------------------------------
// Kernel 1: Y[n, h*256+d] = bf16( a[h,d]*x[n,d] * rsqrt(max(sum_d (a*x)^2, eps)) )
// --------------------------------------------------------------------------
__global__ __launch_bounds__(256) void prep_y(const float* __restrict__ x,
                                              const float* __restrict__ av,
                                              unsigned short* __restrict__ Y) {
  __shared__ float a_sh[HHEADS][DDIM];
  __shared__ float red[4][HHEADS];

  const int t = threadIdx.x;   // 0..255 == d
  #pragma unroll
  for (int h = 0; h < HHEADS; ++h) a_sh[h][t] = av[h * DDIM + t];
  __syncthreads();

  const int n = blockIdx.x;
  const float xd = x[(size_t)n * DDIM + t];

  float p[HHEADS], s[HHEADS];
  #pragma unroll
  for (int h = 0; h < HHEADS; ++h) {
    p[h] = a_sh[h][t] * xd;
    s[h] = p[h] * p[h];
  }

  #pragma unroll
  for (int off = 32; off > 0; off >>= 1) {
    #pragma unroll
    for (int h = 0; h < HHEADS; ++h) s[h] += __shfl_xor(s[h], off, 64);
  }

  const int wave = t >> 6, lane = t & 63;
  if (lane == 0) {
    #pragma unroll
    for (int h = 0; h < HHEADS; ++h) red[wave][h] = s[h];
  }
  __syncthreads();

  #pragma unroll
  for (int h = 0; h < HHEADS; ++h) {
    const float sum = red[0][h] + red[1][h] + red[2][h] + red[3][h];
    const float rn = rsqrtf(fmaxf(sum, 1e-12f));
    Y[(size_t)n * KTOT + h * DDIM + t] = f2bf(p[h] * rn);
  }
}

// --------------------------------------------------------------------------
// Kernel 2: C = Y * Y^T / 4, symmetry-exploiting: only by >= bx tiles computed;
// off-diagonal tiles written twice (straight + LDS-transposed mirror).
// 128x128 tile, BK=64, 4 waves (2x2), 16x16x32 bf16 MFMA.
// NOTE: the mirror loop is FULLY UNROLLED so every acc[][] index is a
// compile-time constant (rule #20: runtime-indexed ext_vector arrays go to
// scratch — that was round 2's 9x write-amplification bug).
// --------------------------------------------------------------------------
union SmemU {
  struct { unsigned short A[BM * BK]; unsigned short B[BN * BK]; } s;  // 32 KB
  float tr[32 * 129];  // transpose slice buffer (16.1 KB), aliases staging
};

__global__ __launch_bounds__(256) void gemm_yyt(const unsigned short* __restrict__ Y,
                                                float* __restrict__ C) {
  __shared__ __attribute__((aligned(16))) SmemU sm;

  // bijective XCD swizzle: NTRI = 2080 = 8 * 260
  const int orig = blockIdx.x;
  const int cpx  = NTRI / 8;
  const int wgid = (orig & 7) * cpx + (orig >> 3);

  // triangular decode: wgid -> (by, bx), bx <= by
  int by = (int)((sqrtf(8.0f * (float)wgid + 1.0f) - 1.0f) * 0.5f);
  while ((by + 1) * (by + 2) / 2 <= wgid) ++by;
  while (by * (by + 1) / 2 > wgid) --by;
  const int bx = wgid - by * (by + 1) / 2;

  const int t    = threadIdx.x;
  const int lane = t & 63;
  const int wave = t >> 6;
  const int wr   = wave >> 1;   // 0..1
  const int wc   = wave & 1;    // 0..1

  const int rowA0 = by * BM;    // output row block
  const int rowB0 = bx * BN;    // output col block

  f32x4 acc[4][4];
  #pragma unroll
  for (int i = 0; i < 4; ++i)
    #pragma unroll
    for (int j = 0; j < 4; ++j) acc[i][j] = (f32x4){0.f, 0.f, 0.f, 0.f};

  for (int kt = 0; kt < KSTEPS; ++kt) {
    const int k0 = kt * BK;
    __syncthreads();  // previous compute done before LDS overwrite

    #pragma unroll
    for (int i = 0; i < 4; ++i) {
      const int s     = i * 256 + t;
      const int row   = s >> 3;
      const int gslot = (s & 7) ^ (row & 7);
      const unsigned short* gsrc = Y + (size_t)(rowA0 + row) * KTOT + k0 + gslot * 8;
      unsigned short* ldst = sm.s.A + s * 8;
      __builtin_amdgcn_global_load_lds(
          (__attribute__((address_space(1))) void*)gsrc,
          (__attribute__((address_space(3))) void*)ldst, 16, 0, 0);
    }
    #pragma unroll
    for (int i = 0; i < 4; ++i) {
      const int s     = i * 256 + t;
      const int row   = s >> 3;
      const int gslot = (s & 7) ^ (row & 7);
      const unsigned short* gsrc = Y + (size_t)(rowB0 + row) * KTOT + k0 + gslot * 8;
      unsigned short* ldst = sm.s.B + s * 8;
      __builtin_amdgcn_global_load_lds(
          (__attribute__((address_space(1))) void*)gsrc,
          (__attribute__((address_space(3))) void*)ldst, 16, 0, 0);
    }
    __syncthreads();

    #pragma unroll
    for (int ks = 0; ks < 2; ++ks) {
      short8 af[4], bfr[4];
      #pragma unroll
      for (int mr = 0; mr < 4; ++mr) {
        const int row  = wr * 64 + mr * 16 + (lane & 15);
        const int slot = (ks * 4 + (lane >> 4)) ^ (row & 7);
        af[mr] = *(const short8*)(sm.s.A + row * BK + slot * 8);
      }
      #pragma unroll
      for (int nr = 0; nr < 4; ++nr) {
        const int row  = wc * 64 + nr * 16 + (lane & 15);
        const int slot = (ks * 4 + (lane >> 4)) ^ (row & 7);
        bfr[nr] = *(const short8*)(sm.s.B + row * BK + slot * 8);
      }
      #pragma unroll
      for (int mr = 0; mr < 4; ++mr)
        #pragma unroll
        for (int nr = 0; nr < 4; ++nr)
          acc[mr][nr] = __builtin_amdgcn_mfma_f32_16x16x32_bf16(
              af[mr], bfr[nr], acc[mr][nr], 0, 0, 0);
    }
  }

  // ---- straight write: C[rowA0 + r][rowB0 + c] ----
  // C/D layout: col = lane&15, row = (lane>>4)*4 + r  (m89/m91)
  const int crow0 = rowA0 + wr * 64;
  const int ccol  = rowB0 + wc * 64 + (lane & 15);
  #pragma unroll
  for (int mr = 0; mr < 4; ++mr) {
    #pragma unroll
    for (int nr = 0; nr < 4; ++nr) {
      #pragma unroll
      for (int r = 0; r < 4; ++r) {
        const int row = crow0 + mr * 16 + (lane >> 4) * 4 + r;
        C[(size_t)row * NROWS + ccol + nr * 16] = acc[mr][nr][r] * 0.25f;
      }
    }
  }

  // ---- mirror write: C[rowB0 + c][rowA0 + r] = tile[r][c], via LDS ----
  // FULLY UNROLLED: c0, nrbase, nr, mr, r are all compile-time constants so
  // acc is never runtime-indexed (stays in AGPRs).
  if (by != bx) {
    float (*tr)[129] = (float(*)[129])sm.tr;
    #pragma unroll
    for (int c0i = 0; c0i < 4; ++c0i) {
      const int c0     = c0i * 32;          // 0, 32, 64, 96  (static)
      const int wcneed = c0 >> 6;           // 0, 0, 1, 1     (static)
      const int nrbase = (c0 & 63) >> 4;    // 0, 2, 0, 2     (static)
      __syncthreads();  // buffer free (covers staging reuse on first iter)
      if (wc == wcneed) {
        #pragma unroll
        for (int nn = 0; nn < 2; ++nn) {
          const int nr = nrbase + nn;                    // static
          const int i  = nn * 16 + (lane & 15);          // c - c0
          #pragma unroll
          for (int mr = 0; mr < 4; ++mr) {
            #pragma unroll
            for (int r = 0; r < 4; ++r) {
              const int j = wr * 64 + mr * 16 + (lane >> 4) * 4 + r;  // r index
              tr[i][j] = acc[mr][nr][r];
            }
          }
        }
      }
      __syncthreads();
      // write 32x128 slice: rows rowB0+c0+ii, cols rowA0+jj (coalesced)
      #pragma unroll
      for (int q = 0; q < 16; ++q) {
        const int idx = q * 256 + t;    // 0..4095
        const int ii  = idx >> 7;
        const int jj  = idx & 127;
        C[(size_t)(rowB0 + c0 + ii) * NROWS + rowA0 + jj] = tr[ii][jj] * 0.25f;
      }
    }
  }
}

// --------------------------------------------------------------------------
extern "C" void kernel_launch(void* const* d_in, const int* in_sizes, int n_in,
                              void* d_out, int out_size, void* d_ws, size_t ws_size,
                              hipStream_t stream) {
  (void)in_sizes; (void)n_in; (void)out_size; (void)ws_size;
  const float* x  = (const float*)d_in[0];   // [8192, 256] f32
  const float* av = (const float*)d_in[1];   // [4, 256] f32
  float* C = (float*)d_out;                  // [8192, 8192] f32
  unsigned short* Y = (unsigned short*)d_ws; // [8192, 1024] bf16 (16 MB scratch)

  prep_y<<<NROWS, 256, 0, stream>>>(x, av, Y);
  gemm_yyt<<<NTRI, 256, 0, stream>>>(Y, C);
}

// Round 4
// 149.110 us; speedup vs baseline: 3.2770x; 1.0061x over previous
//
#include <hip/hip_runtime.h>
#include <hip/hip_bf16.h>
#include <stdint.h>

typedef __attribute__((ext_vector_type(8))) short short8;
typedef __attribute__((ext_vector_type(4))) float f32x4;

#define NROWS  8192
#define DDIM   256
#define HHEADS 4
#define KTOT   1024            // H * D
#define BM     256
#define BN     256
#define BK     64
#define NT     (KTOT / BK)     // 16 K-tiles
#define NTB    (NROWS / BM)    // 32 tile rows
#define NTRI   (NTB * (NTB + 1) / 2)   // 528 triangular tiles

// LDS element offsets (unsigned short units) within one 32K-elem buffer:
//   A-lo: +0      (rows   0..127 x 64)
//   A-hi: +8192   (rows 128..255 x 64)
//   B-lo: +16384
//   B-hi: +24576
// buf b at b*32768 elems. Total 65536 elems = 128 KiB.

#define SBAR()  __builtin_amdgcn_s_barrier()
#define LGKM0() do { asm volatile("s_waitcnt lgkmcnt(0)" ::: "memory"); \
                     __builtin_amdgcn_sched_barrier(0); } while (0)
#define VMCNT(n) do { asm volatile("s_waitcnt vmcnt(" #n ")" ::: "memory"); \
                      __builtin_amdgcn_sched_barrier(0); } while (0)

__device__ __forceinline__ unsigned short f2bf(float f) {
  union { float f; uint32_t u; } v;
  v.f = f;
  uint32_t u = v.u;
  uint32_t r = (u + 0x7fffu + ((u >> 16) & 1u)) >> 16;
  return (unsigned short)r;
}

// --------------------------------------------------------------------------
// Kernel 1: Y[n, h*256+d] = bf16-normalized per-head scaled rows
// --------------------------------------------------------------------------
__global__ __launch_bounds__(256) void prep_y(const float* __restrict__ x,
                                              const float* __restrict__ av,
                                              unsigned short* __restrict__ Y) {
  __shared__ float a_sh[HHEADS][DDIM];
  __shared__ float red[4][HHEADS];

  const int t = threadIdx.x;
  #pragma unroll
  for (int h = 0; h < HHEADS; ++h) a_sh[h][t] = av[h * DDIM + t];
  __syncthreads();

  const int n = blockIdx.x;
  const float xd = x[(size_t)n * DDIM + t];

  float p[HHEADS], s[HHEADS];
  #pragma unroll
  for (int h = 0; h < HHEADS; ++h) { p[h] = a_sh[h][t] * xd; s[h] = p[h] * p[h]; }

  #pragma unroll
  for (int off = 32; off > 0; off >>= 1) {
    #pragma unroll
    for (int h = 0; h < HHEADS; ++h) s[h] += __shfl_xor(s[h], off, 64);
  }

  const int wave = t >> 6, lane = t & 63;
  if (lane == 0) {
    #pragma unroll
    for (int h = 0; h < HHEADS; ++h) red[wave][h] = s[h];
  }
  __syncthreads();

  #pragma unroll
  for (int h = 0; h < HHEADS; ++h) {
    const float sum = red[0][h] + red[1][h] + red[2][h] + red[3][h];
    const float rn = rsqrtf(fmaxf(sum, 1e-12f));
    Y[(size_t)n * KTOT + h * DDIM + t] = f2bf(p[h] * rn);
  }
}

// --------------------------------------------------------------------------
// stage one 128x64 bf16 half-tile: 2 x global_load_lds(16B) per thread.
// Linear LDS dest + inverse-swizzled global source (rule #21); the slot-XOR
// matches the ds_read swizzle (0 bank conflicts, proven r1-r3).
// --------------------------------------------------------------------------
__device__ __forceinline__ void stage_half(const unsigned short* __restrict__ Y,
                                           unsigned short* lds_region,
                                           int grow0, int k0, int tid) {
  #pragma unroll
  for (int i = 0; i < 2; ++i) {
    const int s    = i * 512 + tid;       // 16B slot 0..1023
    const int srow = s >> 3;              // 0..127
    const int gsl  = (s & 7) ^ (srow & 7);
    const unsigned short* gsrc =
        Y + (size_t)(grow0 + srow) * KTOT + k0 + gsl * 8;
    __builtin_amdgcn_global_load_lds(
        (const __attribute__((address_space(1))) void*)gsrc,
        (__attribute__((address_space(3))) void*)(lds_region + s * 8), 16, 0, 0);
  }
}

// --------------------------------------------------------------------------
// Kernel 2: C = Y*Y^T / 4 on triangular 256x256 tile grid, 8-phase schedule.
// 8 waves (2M x 4N), per-wave output 128x64, BK=64, double-buffered 128K LDS.
// Ledger (group computing tile T, phases a-d = quadrants 0-3):
//   a: issue A-lo(T+1)->buf[T+1]   (vacated at group T-1 end barrier)
//   b: issue A-hi(T+1)->buf[T+1]
//   c: issue B-lo(T+2)->buf[T]     (B of buf[T] vacated after phase a)
//   d: issue B-hi(T+2)->buf[T]; vmcnt(4) -> K(T+1) complete, 2 halves fly
// --------------------------------------------------------------------------
__global__ __launch_bounds__(512, 2) void gemm_yyt(const unsigned short* __restrict__ Y,
                                                   float* __restrict__ C) {
  __shared__ __attribute__((aligned(16))) unsigned short lds[65536];  // 128 KiB

  // bijective XCD swizzle: 528 = 8 * 66
  const int orig = blockIdx.x;
  const int wgid = (orig & 7) * (NTRI / 8) + (orig >> 3);

  int by = (int)((sqrtf(8.0f * (float)wgid + 1.0f) - 1.0f) * 0.5f);
  while ((by + 1) * (by + 2) / 2 <= wgid) ++by;
  while (by * (by + 1) / 2 > wgid) --by;
  const int bx = wgid - by * (by + 1) / 2;

  const int tid  = threadIdx.x;
  const int lane = tid & 63;
  const int wv   = tid >> 6;
  const int wr   = wv >> 2;       // 0..1  (M)
  const int wn   = wv & 3;        // 0..3  (N)
  const int l15  = lane & 15;
  const int lh   = lane >> 4;     // 0..3

  const int rowA0 = by * BM;
  const int rowB0 = bx * BN;

  const int arow = wr * 128 + l15;   // local A row base
  const int brow = wn * 64 + l15;    // local B row base
  const int slA0 = (0 + lh) ^ (arow & 7), slA1 = (4 + lh) ^ (arow & 7);
  const int slB0 = (0 + lh) ^ (brow & 7), slB1 = (4 + lh) ^ (brow & 7);

  f32x4 acc[8][4];
  #pragma unroll
  for (int m = 0; m < 8; ++m)
    #pragma unroll
    for (int n = 0; n < 4; ++n) acc[m][n] = (f32x4){0.f, 0.f, 0.f, 0.f};

  // ---------------- prologue: K0 all 4 halves + B halves of K1 ----------
  stage_half(Y, lds + 0,             rowA0,       0,  tid);  // A-lo(0)
  stage_half(Y, lds + 8192,          rowA0 + 128, 0,  tid);  // A-hi(0)
  stage_half(Y, lds + 16384,         rowB0,       0,  tid);  // B-lo(0)
  stage_half(Y, lds + 24576,         rowB0 + 128, 0,  tid);  // B-hi(0)
  stage_half(Y, lds + 32768 + 16384, rowB0,       64, tid);  // B-lo(1)
  stage_half(Y, lds + 32768 + 24576, rowB0 + 128, 64, tid);  // B-hi(1)
  VMCNT(4);   // K0 complete; B(1) may fly
  SBAR();

  short8 bf[4][2], af[2][2];

#define READ_A(q) do {                                                        \
    _Pragma("unroll")                                                         \
    for (int mm = 0; mm < 2; ++mm) {                                          \
      const int r_ = arow + ((q) * 2 + mm) * 16;                              \
      af[mm][0] = *(const short8*)(lds + cur + r_ * 64 + slA0 * 8);           \
      af[mm][1] = *(const short8*)(lds + cur + r_ * 64 + slA1 * 8);           \
    }                                                                         \
  } while (0)

#define MFMA_QUAD(q) do {                                                     \
    __builtin_amdgcn_s_setprio(1);                                            \
    _Pragma("unroll")                                                         \
    for (int mm = 0; mm < 2; ++mm)                                            \
      _Pragma("unroll")                                                       \
      for (int n = 0; n < 4; ++n) {                                           \
        acc[(q)*2+mm][n] = __builtin_amdgcn_mfma_f32_16x16x32_bf16(           \
            af[mm][0], bf[n][0], acc[(q)*2+mm][n], 0, 0, 0);                  \
        acc[(q)*2+mm][n] = __builtin_amdgcn_mfma_f32_16x16x32_bf16(           \
            af[mm][1], bf[n][1], acc[(q)*2+mm][n], 0, 0, 0);                  \
      }                                                                       \
    __builtin_amdgcn_s_setprio(0);                                            \
  } while (0)

  for (int T = 0; T < NT; ++T) {
    const int cur = (T & 1) << 15;
    const int nxt = ((T + 1) & 1) << 15;
    const int k1  = (T + 1) * BK;
    const int k2  = (T + 2) * BK;

    // ---- phase a (quadrant 0): B frags + A m0,m1 ----
    if (T + 1 < NT) stage_half(Y, lds + nxt, rowA0, k1, tid);        // A-lo(T+1)
    #pragma unroll
    for (int n = 0; n < 4; ++n) {
      const int r_ = brow + n * 16;
      bf[n][0] = *(const short8*)(lds + cur + 16384 + r_ * 64 + slB0 * 8);
      bf[n][1] = *(const short8*)(lds + cur + 16384 + r_ * 64 + slB1 * 8);
    }
    READ_A(0);
    __builtin_amdgcn_sched_barrier(0);
    SBAR(); LGKM0();
    MFMA_QUAD(0);
    __builtin_amdgcn_sched_barrier(0);
    SBAR();

    // ---- phase b (quadrant 1) ----
    if (T + 1 < NT) stage_half(Y, lds + nxt + 8192, rowA0 + 128, k1, tid);  // A-hi(T+1)
    READ_A(1);
    __builtin_amdgcn_sched_barrier(0);
    SBAR(); LGKM0();
    MFMA_QUAD(1);
    __builtin_amdgcn_sched_barrier(0);
    SBAR();

    // ---- phase c (quadrant 2) ----
    if (T + 2 < NT) stage_half(Y, lds + cur + 16384, rowB0, k2, tid);       // B-lo(T+2)
    READ_A(2);
    __builtin_amdgcn_sched_barrier(0);
    SBAR(); LGKM0();
    MFMA_QUAD(2);
    __builtin_amdgcn_sched_barrier(0);
    SBAR();

    // ---- phase d (quadrant 3) ----
    if (T + 2 < NT) stage_half(Y, lds + cur + 24576, rowB0 + 128, k2, tid); // B-hi(T+2)
    READ_A(3);
    __builtin_amdgcn_sched_barrier(0);
    SBAR(); LGKM0();
    MFMA_QUAD(3);
    __builtin_amdgcn_sched_barrier(0);
    if (T < NT - 2) { VMCNT(4); } else { VMCNT(0); }  // K(T+1) complete
    SBAR();
  }

  // ---------------- epilogue ----------------
  // mirror first (stores drain behind later work), straight write last.
  if (by != bx) {
    float (*tr)[257] = (float(*)[257])lds;   // 64 x 257 f32 = 65.8 KB
    #pragma unroll
    for (int s = 0; s < 4; ++s) {
      if (s > 0) __syncthreads();
      if (wn == s) {
        #pragma unroll
        for (int m = 0; m < 8; ++m)
          #pragma unroll
          for (int n = 0; n < 4; ++n)
            #pragma unroll
            for (int r = 0; r < 4; ++r) {
              const int cl = n * 16 + l15;                      // 0..63
              const int rl = wr * 128 + m * 16 + lh * 4 + r;    // 0..255
              tr[cl][rl] = acc[m][n][r];
            }
      }
      __syncthreads();
      #pragma unroll
      for (int q = 0; q < 8; ++q) {
        const int idx = q * 512 + tid;        // 0..4095
        const int ii  = idx >> 6;             // 0..63
        const int jj  = (idx & 63) * 4;       // 0..252
        f32x4 v = { tr[ii][jj] * 0.25f, tr[ii][jj + 1] * 0.25f,
                    tr[ii][jj + 2] * 0.25f, tr[ii][jj + 3] * 0.25f };
        *(f32x4*)(C + (size_t)(rowB0 + s * 64 + ii) * NROWS + rowA0 + jj) = v;
      }
    }
  }

  // straight write: row = rowA0 + wr*128 + m*16 + lh*4 + r, col = rowB0 + wn*64 + n*16 + l15
  const int crow0 = rowA0 + wr * 128;
  const int ccol  = rowB0 + wn * 64 + l15;
  #pragma unroll
  for (int m = 0; m < 8; ++m)
    #pragma unroll
    for (int n = 0; n < 4; ++n)
      #pragma unroll
      for (int r = 0; r < 4; ++r) {
        const int row = crow0 + m * 16 + lh * 4 + r;
        C[(size_t)row * NROWS + ccol + n * 16] = acc[m][n][r] * 0.25f;
      }
}

// --------------------------------------------------------------------------
extern "C" void kernel_launch(void* const* d_in, const int* in_sizes, int n_in,
                              void* d_out, int out_size, void* d_ws, size_t ws_size,
                              hipStream_t stream) {
  (void)in_sizes; (void)n_in; (void)out_size; (void)ws_size;
  const float* x  = (const float*)d_in[0];   // [8192, 256] f32
  const float* av = (const float*)d_in[1];   // [4, 256] f32
  float* C = (float*)d_out;                  // [8192, 8192] f32
  unsigned short* Y = (unsigned short*)d_ws; // [8192, 1024] bf16 scratch

  prep_y<<<NROWS, 256, 0, stream>>>(x, av, Y);
  gemm_yyt<<<NTRI, 512, 0, stream>>>(Y, C);
}

// Round 5
// 147.315 us; speedup vs baseline: 3.3169x; 1.0122x over previous
//
#include <hip/hip_runtime.h>
#include <hip/hip_bf16.h>
#include <stdint.h>

typedef __attribute__((ext_vector_type(8))) short short8;
typedef __attribute__((ext_vector_type(4))) float f32x4;

#define NROWS  8192
#define DDIM   256
#define HHEADS 4
#define KTOT   1024            // H * D
#define BM     256
#define BN     256
#define BK     64
#define NT     (KTOT / BK)     // 16 K-tiles
#define NTB    (NROWS / BM)    // 32 tile rows
#define NTRI   (NTB * (NTB + 1) / 2)   // 528 triangular tiles

// LDS element offsets (unsigned short units) within one 32K-elem buffer:
//   A-lo: +0      (rows   0..127 x 64)
//   A-hi: +8192   (rows 128..255 x 64)
//   B-lo: +16384
//   B-hi: +24576
// buf b at b*32768 elems. Total 65536 elems = 128 KiB.

#define SBAR()  __builtin_amdgcn_s_barrier()
#define LGKM0() do { asm volatile("s_waitcnt lgkmcnt(0)" ::: "memory"); \
                     __builtin_amdgcn_sched_barrier(0); } while (0)
#define VMCNT(n) do { asm volatile("s_waitcnt vmcnt(" #n ")" ::: "memory"); \
                      __builtin_amdgcn_sched_barrier(0); } while (0)

__device__ __forceinline__ unsigned short f2bf(float f) {
  union { float f; uint32_t u; } v;
  v.f = f;
  uint32_t u = v.u;
  uint32_t r = (u + 0x7fffu + ((u >> 16) & 1u)) >> 16;
  return (unsigned short)r;
}

// --------------------------------------------------------------------------
// Kernel 1: Y[n, h*256+d] = bf16-normalized per-head scaled rows
// --------------------------------------------------------------------------
__global__ __launch_bounds__(256) void prep_y(const float* __restrict__ x,
                                              const float* __restrict__ av,
                                              unsigned short* __restrict__ Y) {
  __shared__ float a_sh[HHEADS][DDIM];
  __shared__ float red[4][HHEADS];

  const int t = threadIdx.x;
  #pragma unroll
  for (int h = 0; h < HHEADS; ++h) a_sh[h][t] = av[h * DDIM + t];
  __syncthreads();

  const int n = blockIdx.x;
  const float xd = x[(size_t)n * DDIM + t];

  float p[HHEADS], s[HHEADS];
  #pragma unroll
  for (int h = 0; h < HHEADS; ++h) { p[h] = a_sh[h][t] * xd; s[h] = p[h] * p[h]; }

  #pragma unroll
  for (int off = 32; off > 0; off >>= 1) {
    #pragma unroll
    for (int h = 0; h < HHEADS; ++h) s[h] += __shfl_xor(s[h], off, 64);
  }

  const int wave = t >> 6, lane = t & 63;
  if (lane == 0) {
    #pragma unroll
    for (int h = 0; h < HHEADS; ++h) red[wave][h] = s[h];
  }
  __syncthreads();

  #pragma unroll
  for (int h = 0; h < HHEADS; ++h) {
    const float sum = red[0][h] + red[1][h] + red[2][h] + red[3][h];
    const float rn = rsqrtf(fmaxf(sum, 1e-12f));
    Y[(size_t)n * KTOT + h * DDIM + t] = f2bf(p[h] * rn);
  }
}

// --------------------------------------------------------------------------
// stage one 128x64 bf16 half-tile: 2 x global_load_lds(16B) per thread.
// Linear LDS dest + inverse-swizzled global source (rule #21); the slot-XOR
// matches the ds_read swizzle (0 bank conflicts, proven r1-r3).
// --------------------------------------------------------------------------
__device__ __forceinline__ void stage_half(const unsigned short* __restrict__ Y,
                                           unsigned short* lds_region,
                                           int grow0, int k0, int tid) {
  #pragma unroll
  for (int i = 0; i < 2; ++i) {
    const int s    = i * 512 + tid;       // 16B slot 0..1023
    const int srow = s >> 3;              // 0..127
    const int gsl  = (s & 7) ^ (srow & 7);
    const unsigned short* gsrc =
        Y + (size_t)(grow0 + srow) * KTOT + k0 + gsl * 8;
    __builtin_amdgcn_global_load_lds(
        (const __attribute__((address_space(1))) void*)gsrc,
        (__attribute__((address_space(3))) void*)(lds_region + s * 8), 16, 0, 0);
  }
}

// --------------------------------------------------------------------------
// Kernel 2: C = Y*Y^T / 4 on triangular 256x256 tile grid, 8-phase schedule.
// 8 waves (2M x 4N), per-wave output 128x64, BK=64, double-buffered 128K LDS.
// Ledger (group computing tile T, phases a-d = quadrants 0-3):
//   a: issue A-lo(T+1)->buf[T+1]   (vacated at group T-1 end barrier)
//   b: issue A-hi(T+1)->buf[T+1]
//   c: issue B-lo(T+2)->buf[T]     (B of buf[T] vacated after phase a)
//   d: issue B-hi(T+2)->buf[T]; vmcnt(4) -> K(T+1) complete, 2 halves fly
// --------------------------------------------------------------------------
__global__ __launch_bounds__(512, 2) void gemm_yyt(const unsigned short* __restrict__ Y,
                                                   float* __restrict__ C) {
  __shared__ __attribute__((aligned(16))) unsigned short lds[65536];  // 128 KiB

  // bijective XCD swizzle: 528 = 8 * 66
  const int orig = blockIdx.x;
  const int wgid = (orig & 7) * (NTRI / 8) + (orig >> 3);

  int by = (int)((sqrtf(8.0f * (float)wgid + 1.0f) - 1.0f) * 0.5f);
  while ((by + 1) * (by + 2) / 2 <= wgid) ++by;
  while (by * (by + 1) / 2 > wgid) --by;
  const int bx = wgid - by * (by + 1) / 2;

  const int tid  = threadIdx.x;
  const int lane = tid & 63;
  const int wv   = tid >> 6;
  const int wr   = wv >> 2;       // 0..1  (M)
  const int wn   = wv & 3;        // 0..3  (N)
  const int l15  = lane & 15;
  const int lh   = lane >> 4;     // 0..3

  const int rowA0 = by * BM;
  const int rowB0 = bx * BN;

  const int arow = wr * 128 + l15;   // local A row base
  const int brow = wn * 64 + l15;    // local B row base
  const int slA0 = (0 + lh) ^ (arow & 7), slA1 = (4 + lh) ^ (arow & 7);
  const int slB0 = (0 + lh) ^ (brow & 7), slB1 = (4 + lh) ^ (brow & 7);

  f32x4 acc[8][4];
  #pragma unroll
  for (int m = 0; m < 8; ++m)
    #pragma unroll
    for (int n = 0; n < 4; ++n) acc[m][n] = (f32x4){0.f, 0.f, 0.f, 0.f};

  // ---------------- prologue: K0 all 4 halves + B halves of K1 ----------
  stage_half(Y, lds + 0,             rowA0,       0,  tid);  // A-lo(0)
  stage_half(Y, lds + 8192,          rowA0 + 128, 0,  tid);  // A-hi(0)
  stage_half(Y, lds + 16384,         rowB0,       0,  tid);  // B-lo(0)
  stage_half(Y, lds + 24576,         rowB0 + 128, 0,  tid);  // B-hi(0)
  stage_half(Y, lds + 32768 + 16384, rowB0,       64, tid);  // B-lo(1)
  stage_half(Y, lds + 32768 + 24576, rowB0 + 128, 64, tid);  // B-hi(1)
  VMCNT(4);   // K0 complete; B(1) may fly
  SBAR();

  short8 bf[4][2], af[2][2];

#define READ_A(q) do {                                                        \
    _Pragma("unroll")                                                         \
    for (int mm = 0; mm < 2; ++mm) {                                          \
      const int r_ = arow + ((q) * 2 + mm) * 16;                              \
      af[mm][0] = *(const short8*)(lds + cur + r_ * 64 + slA0 * 8);           \
      af[mm][1] = *(const short8*)(lds + cur + r_ * 64 + slA1 * 8);           \
    }                                                                         \
  } while (0)

#define MFMA_QUAD(q) do {                                                     \
    __builtin_amdgcn_s_setprio(1);                                            \
    _Pragma("unroll")                                                         \
    for (int mm = 0; mm < 2; ++mm)                                            \
      _Pragma("unroll")                                                       \
      for (int n = 0; n < 4; ++n) {                                           \
        acc[(q)*2+mm][n] = __builtin_amdgcn_mfma_f32_16x16x32_bf16(           \
            af[mm][0], bf[n][0], acc[(q)*2+mm][n], 0, 0, 0);                  \
        acc[(q)*2+mm][n] = __builtin_amdgcn_mfma_f32_16x16x32_bf16(           \
            af[mm][1], bf[n][1], acc[(q)*2+mm][n], 0, 0, 0);                  \
      }                                                                       \
    __builtin_amdgcn_s_setprio(0);                                            \
  } while (0)

  for (int T = 0; T < NT; ++T) {
    const int cur = (T & 1) << 15;
    const int nxt = ((T + 1) & 1) << 15;
    const int k1  = (T + 1) * BK;
    const int k2  = (T + 2) * BK;

    // ---- phase a (quadrant 0): B frags + A m0,m1 ----
    if (T + 1 < NT) stage_half(Y, lds + nxt, rowA0, k1, tid);        // A-lo(T+1)
    #pragma unroll
    for (int n = 0; n < 4; ++n) {
      const int r_ = brow + n * 16;
      bf[n][0] = *(const short8*)(lds + cur + 16384 + r_ * 64 + slB0 * 8);
      bf[n][1] = *(const short8*)(lds + cur + 16384 + r_ * 64 + slB1 * 8);
    }
    READ_A(0);
    __builtin_amdgcn_sched_barrier(0);
    SBAR(); LGKM0();
    MFMA_QUAD(0);
    __builtin_amdgcn_sched_barrier(0);
    SBAR();

    // ---- phase b (quadrant 1) ----
    if (T + 1 < NT) stage_half(Y, lds + nxt + 8192, rowA0 + 128, k1, tid);  // A-hi(T+1)
    READ_A(1);
    __builtin_amdgcn_sched_barrier(0);
    SBAR(); LGKM0();
    MFMA_QUAD(1);
    __builtin_amdgcn_sched_barrier(0);
    SBAR();

    // ---- phase c (quadrant 2) ----
    if (T + 2 < NT) stage_half(Y, lds + cur + 16384, rowB0, k2, tid);       // B-lo(T+2)
    READ_A(2);
    __builtin_amdgcn_sched_barrier(0);
    SBAR(); LGKM0();
    MFMA_QUAD(2);
    __builtin_amdgcn_sched_barrier(0);
    SBAR();

    // ---- phase d (quadrant 3) ----
    if (T + 2 < NT) stage_half(Y, lds + cur + 24576, rowB0 + 128, k2, tid); // B-hi(T+2)
    READ_A(3);
    __builtin_amdgcn_sched_barrier(0);
    SBAR(); LGKM0();
    MFMA_QUAD(3);
    __builtin_amdgcn_sched_barrier(0);
    if (T < NT - 2) { VMCNT(4); } else { VMCNT(0); }  // K(T+1) complete
    SBAR();
  }

  // ---------------- epilogue ----------------
  // mirror first (stores drain behind later work), straight write last.
  if (by != bx) {
    float (*tr)[257] = (float(*)[257])lds;   // 64 x 257 f32 = 65.8 KB
    #pragma unroll
    for (int s = 0; s < 4; ++s) {
      if (s > 0) __syncthreads();
      if (wn == s) {
        #pragma unroll
        for (int m = 0; m < 8; ++m)
          #pragma unroll
          for (int n = 0; n < 4; ++n)
            #pragma unroll
            for (int r = 0; r < 4; ++r) {
              const int cl = n * 16 + l15;                      // 0..63
              const int rl = wr * 128 + m * 16 + lh * 4 + r;    // 0..255
              tr[cl][rl] = acc[m][n][r];
            }
      }
      __syncthreads();
      #pragma unroll
      for (int q = 0; q < 8; ++q) {
        const int idx = q * 512 + tid;        // 0..4095
        const int ii  = idx >> 6;             // 0..63
        const int jj  = (idx & 63) * 4;       // 0..252
        f32x4 v = { tr[ii][jj] * 0.25f, tr[ii][jj + 1] * 0.25f,
                    tr[ii][jj + 2] * 0.25f, tr[ii][jj + 3] * 0.25f };
        *(f32x4*)(C + (size_t)(rowB0 + s * 64 + ii) * NROWS + rowA0 + jj) = v;
      }
    }
  }

  // straight write: row = rowA0 + wr*128 + m*16 + lh*4 + r, col = rowB0 + wn*64 + n*16 + l15
  const int crow0 = rowA0 + wr * 128;
  const int ccol  = rowB0 + wn * 64 + l15;
  #pragma unroll
  for (int m = 0; m < 8; ++m)
    #pragma unroll
    for (int n = 0; n < 4; ++n)
      #pragma unroll
      for (int r = 0; r < 4; ++r) {
        const int row = crow0 + m * 16 + lh * 4 + r;
        C[(size_t)row * NROWS + ccol + n * 16] = acc[m][n][r] * 0.25f;
      }
}

// --------------------------------------------------------------------------
extern "C" void kernel_launch(void* const* d_in, const int* in_sizes, int n_in,
                              void* d_out, int out_size, void* d_ws, size_t ws_size,
                              hipStream_t stream) {
  (void)in_sizes; (void)n_in; (void)out_size; (void)ws_size;
  const float* x  = (const float*)d_in[0];   // [8192, 256] f32
  const float* av = (const float*)d_in[1];   // [4, 256] f32
  float* C = (float*)d_out;                  // [8192, 8192] f32
  unsigned short* Y = (unsigned short*)d_ws; // [8192, 1024] bf16 scratch

  prep_y<<<NROWS, 256, 0, stream>>>(x, av, Y);
  gemm_yyt<<<NTRI, 512, 0, stream>>>(Y, C);
}